// Round 11
// baseline (300.879 us; speedup 1.0000x reference)
//
#include <hip/hip_runtime.h>
#include <hip/hip_bf16.h>

#define BN 8
#define CN 256
#define CQn 32
#define HN 128
#define WN 128

using bf16 = __hip_bfloat16;
typedef short short8 __attribute__((ext_vector_type(8)));
typedef float f32x4 __attribute__((ext_vector_type(4)));

__device__ __forceinline__ unsigned short f2bu(float v) {
  bf16 h = __float2bfloat16(v);
  return *(unsigned short*)&h;
}
__device__ __forceinline__ float bu2f(unsigned short u) {
  return __bfloat162float(*(const bf16*)&u);
}
__device__ __forceinline__ unsigned pack2(float a, float b) {
  return (unsigned)f2bu(a) | ((unsigned)f2bu(b) << 16);
}
__device__ __forceinline__ uint4 add8bf16(uint4 a, uint4 b) {
  union { uint4 v; unsigned short u[8]; } A, B, C;
  A.v = a; B.v = b;
#pragma unroll
  for (int e = 0; e < 8; ++e) C.u[e] = f2bu(bu2f(A.u[e]) + bu2f(B.u[e]));
  return C.v;
}

// ---- MFMA projection: qF/kF[b][h][w][32c] bf16, plus xbf[b][c][h][w] bf16 copy of x.
__global__ __launch_bounds__(256) void proj_qk3(
    const float* __restrict__ x, const float* __restrict__ Wq, const float* __restrict__ bq,
    const float* __restrict__ Wk, const float* __restrict__ bk,
    bf16* __restrict__ qF, bf16* __restrict__ kF, bf16* __restrict__ xbf) {
  __shared__ unsigned short xs[256 * 64];   // [c][w-local]; row=128B -> col reads 2-way (free)
  __shared__ unsigned short Ws[64 * 256];   // [oc][c], 16B-chunk swizzle slot = cg ^ (oc&7)
  const int tid = threadIdx.x;
  const int half = blockIdx.x & 1;
  const int bh = blockIdx.x >> 1;
  const int b = bh >> 7, h = bh & 127;
  const int w0 = half * 64;

#pragma unroll
  for (int it = 0; it < 8; ++it) {
    int idx = it * 256 + tid;           // 0..2047
    int oc = idx >> 5, cg = idx & 31;
    const float* wp = (oc < 32) ? &Wq[(size_t)oc * 256 + cg * 8]
                                : &Wk[(size_t)(oc - 32) * 256 + cg * 8];
    float4 f0 = *(const float4*)wp;
    float4 f1 = *(const float4*)(wp + 4);
    union { unsigned short u[8]; uint4 v; } t;
    t.u[0] = f2bu(f0.x); t.u[1] = f2bu(f0.y); t.u[2] = f2bu(f0.z); t.u[3] = f2bu(f0.w);
    t.u[4] = f2bu(f1.x); t.u[5] = f2bu(f1.y); t.u[6] = f2bu(f1.z); t.u[7] = f2bu(f1.w);
    *(uint4*)&Ws[oc * 256 + (cg ^ (oc & 7)) * 8] = t.v;
  }
  unsigned short* xbu = (unsigned short*)xbf;
#pragma unroll
  for (int it = 0; it < 16; ++it) {
    int idx = it * 256 + tid;           // 0..4095
    int c = idx >> 4, wc = idx & 15;
    size_t gix = (((size_t)b * 256 + c) * 128 + h) * 128 + w0 + wc * 4;
    float4 f = *(const float4*)&x[gix];
    union { unsigned short u[4]; uint2 v; } t;
    t.u[0] = f2bu(f.x); t.u[1] = f2bu(f.y); t.u[2] = f2bu(f.z); t.u[3] = f2bu(f.w);
    *(uint2*)&xs[c * 64 + wc * 4] = t.v;
    *(uint2*)&xbu[gix] = t.v;
  }
  __syncthreads();

  const int lane = tid & 63, wid = tid >> 6;  // 4 waves, each owns 16 w
  const int l15 = lane & 15, lg = lane >> 4;
  f32x4 acc[4];
#pragma unroll
  for (int mt = 0; mt < 4; ++mt)
#pragma unroll
    for (int e = 0; e < 4; ++e) acc[mt][e] = 0.f;

#pragma unroll
  for (int ks = 0; ks < 8; ++ks) {
    union { unsigned short u[8]; short8 s; } bf;
#pragma unroll
    for (int e = 0; e < 8; ++e)
      bf.u[e] = xs[(ks * 32 + lg * 8 + e) * 64 + wid * 16 + l15];
#pragma unroll
    for (int mt = 0; mt < 4; ++mt) {
      int oc = mt * 16 + l15;
      short8 af = *(const short8*)&Ws[oc * 256 + ((ks * 4 + lg) ^ (oc & 7)) * 8];
      acc[mt] = __builtin_amdgcn_mfma_f32_16x16x32_bf16(af, bf.s, acc[mt], 0, 0, 0);
    }
  }

  const int w = w0 + wid * 16 + l15;
#pragma unroll
  for (int mt = 0; mt < 4; ++mt) {
    float bb[4];
#pragma unroll
    for (int rr = 0; rr < 4; ++rr) {
      int ch = (mt & 1) * 16 + lg * 4 + rr;
      bb[rr] = (mt < 2) ? bq[ch] : bk[ch];
    }
    uint2 v;
    v.x = pack2(acc[mt][0] + bb[0], acc[mt][1] + bb[1]);
    v.y = pack2(acc[mt][2] + bb[2], acc[mt][3] + bb[3]);
    size_t base = (((size_t)b * 128 + h) * 128 + w) * 32 + (mt & 1) * 16 + lg * 4;
    if (mt < 2) *(uint2*)&((unsigned short*)qF)[base] = v;
    else        *(uint2*)&((unsigned short*)kF)[base] = v;
  }
}

// ---- transpose body: [p][r][c] -> [p][c][r] bf16, tile = float[32*33] in LDS
__device__ __forceinline__ void transpose_body(float* tile, const bf16* __restrict__ in,
                                               bf16* __restrict__ out, int blk) {
  const int p = blk >> 4, t = blk & 15;
  const int r0 = (t >> 2) * 32, c0 = (t & 3) * 32;
  const int tx = threadIdx.x & 31, ty = threadIdx.x >> 5;
  const bf16* ip = in + (size_t)p * 128 * 128;
#pragma unroll
  for (int rr = 0; rr < 4; ++rr)
    tile[(ty + 8 * rr) * 33 + tx] = __bfloat162float(ip[(r0 + ty + 8 * rr) * 128 + c0 + tx]);
  __syncthreads();
  bf16* op = out + (size_t)p * 128 * 128;
#pragma unroll
  for (int rr = 0; rr < 4; ++rr)
    op[(c0 + ty + 8 * rr) * 128 + r0 + tx] = __float2bfloat16(tile[tx * 33 + ty + 8 * rr]);
}

// ---- MFMA criss-cross 1D attention body (V source bf16). psm = 32768B, rsum = 512B.
template <bool COL>
__device__ __forceinline__ void attn_body(
    unsigned short* psm, float* rsum,
    const bf16* __restrict__ qF, const bf16* __restrict__ kF,
    const bf16* __restrict__ vsrc, bf16* __restrict__ outP, int blk) {
  const int tid = threadIdx.x;
  const int wid = tid >> 6;
  const int lane = tid & 63;
  const int l15 = lane & 15, lg = lane >> 4;
  const int b = blk >> 7, r = blk & 127;

  short8 qf[2];
  const int ti0 = wid * 2;
#pragma unroll
  for (int t2 = 0; t2 < 2; ++t2) {
    int i = (ti0 + t2) * 16 + l15;
    size_t base = COL ? (((size_t)b * 128 + i) * 128 + r) * 32
                      : (((size_t)b * 128 + r) * 128 + i) * 32;
    qf[t2] = *(const short8*)&qF[base + lg * 8];
  }
  f32x4 lgt[2][8];
#pragma unroll
  for (int t2 = 0; t2 < 2; ++t2)
#pragma unroll
    for (int tj = 0; tj < 8; ++tj)
#pragma unroll
      for (int e = 0; e < 4; ++e) lgt[t2][tj][e] = 0.f;
#pragma unroll
  for (int tj = 0; tj < 8; ++tj) {
    int j = tj * 16 + l15;
    size_t base = COL ? (((size_t)b * 128 + j) * 128 + r) * 32
                      : (((size_t)b * 128 + r) * 128 + j) * 32;
    short8 kf = *(const short8*)&kF[base + lg * 8];
#pragma unroll
    for (int t2 = 0; t2 < 2; ++t2)
      lgt[t2][tj] = __builtin_amdgcn_mfma_f32_16x16x32_bf16(kf, qf[t2], lgt[t2][tj], 0, 0, 0);
  }

#pragma unroll
  for (int t2 = 0; t2 < 2; ++t2) {
    const int i = (ti0 + t2) * 16 + l15;
    if (COL) {
#pragma unroll
      for (int tj = 0; tj < 8; ++tj)
#pragma unroll
        for (int rr = 0; rr < 4; ++rr)
          if (tj * 16 + lg * 4 + rr == i) lgt[t2][tj][rr] += 1.0f;
    }
    float m = -1e30f;
#pragma unroll
    for (int tj = 0; tj < 8; ++tj)
#pragma unroll
      for (int rr = 0; rr < 4; ++rr) m = fmaxf(m, lgt[t2][tj][rr]);
    m = fmaxf(m, __shfl_xor(m, 16, 64));
    m = fmaxf(m, __shfl_xor(m, 32, 64));
    float s = 0.f;
#pragma unroll
    for (int tj = 0; tj < 8; ++tj)
#pragma unroll
      for (int rr = 0; rr < 4; ++rr) {
        float e = __expf(lgt[t2][tj][rr] - m);
        lgt[t2][tj][rr] = e;
        s += e;
      }
    s += __shfl_xor(s, 16, 64);
    s += __shfl_xor(s, 32, 64);
    if (lg == 0) rsum[i] = s;
#pragma unroll
    for (int tj = 0; tj < 8; ++tj) {
      int slot = ((tj * 2) + (lg >> 1)) ^ (i & 7);
      int elem = i * 128 + slot * 8 + (lg & 1) * 4;
      uint2 v;
      v.x = pack2(lgt[t2][tj][0], lgt[t2][tj][1]);
      v.y = pack2(lgt[t2][tj][2], lgt[t2][tj][3]);
      *(uint2*)&psm[elem] = v;
    }
  }
  __syncthreads();

  float rinv[8];
#pragma unroll
  for (int nt = 0; nt < 8; ++nt) rinv[nt] = 1.0f / rsum[nt * 16 + l15];

  const int cbase = wid * 64;
  unsigned short* ou = (unsigned short*)outP;
#pragma unroll
  for (int cp = 0; cp < 2; ++cp) {
    short8 vf[2][4];
#pragma unroll
    for (int u = 0; u < 2; ++u) {
      int c = cbase + (cp * 2 + u) * 16 + l15;
#pragma unroll
      for (int ks = 0; ks < 4; ++ks)
        vf[u][ks] = *(const short8*)&vsrc[(((size_t)b * 256 + c) * 128 + r) * 128 + ks * 32 + lg * 8];
    }
    f32x4 acc[2][8];
#pragma unroll
    for (int u = 0; u < 2; ++u)
#pragma unroll
      for (int nt = 0; nt < 8; ++nt)
#pragma unroll
        for (int e = 0; e < 4; ++e) acc[u][nt][e] = 0.f;
#pragma unroll
    for (int ks = 0; ks < 4; ++ks)
#pragma unroll
      for (int nt = 0; nt < 8; ++nt) {
        int i = nt * 16 + l15;
        short8 pf = *(const short8*)&psm[i * 128 + (((ks * 4) + lg) ^ (i & 7)) * 8];
#pragma unroll
        for (int u = 0; u < 2; ++u)
          acc[u][nt] = __builtin_amdgcn_mfma_f32_16x16x32_bf16(vf[u][ks], pf, acc[u][nt], 0, 0, 0);
      }
#pragma unroll
    for (int u = 0; u < 2; ++u) {
      int ct = cp * 2 + u;
      int cg = wid * 8 + ct * 2 + (lg >> 1);
#pragma unroll
      for (int nt = 0; nt < 8; ++nt) {
        int i = nt * 16 + l15;
        float sc = rinv[nt];
        uint2 v;
        v.x = pack2(acc[u][nt][0] * sc, acc[u][nt][1] * sc);
        v.y = pack2(acc[u][nt][2] * sc, acc[u][nt][3] * sc);
        size_t elem = ((((size_t)b * 32 + cg) * 128 + r) * 128 + i) * 8 + (lg & 1) * 4;
        *(uint2*)&ou[elem] = v;
      }
    }
  }
}

// ---- fused mid kernel: [0,1024) attn_row | [1024,5120) transpose xbf->xT | [5120,5376) Wv->bf16
__global__ __launch_bounds__(256) void fused_mid(
    const bf16* __restrict__ qF, const bf16* __restrict__ kF,
    const bf16* __restrict__ xbf, bf16* __restrict__ twP, bf16* __restrict__ xT,
    const float* __restrict__ Wv, bf16* __restrict__ Wvb) {
  __shared__ __align__(16) char smem[32768 + 512];
  const int blk = blockIdx.x;
  if (blk < BN * HN) {
    attn_body<false>((unsigned short*)smem, (float*)(smem + 32768), qF, kF, xbf, twP, blk);
  } else if (blk < BN * HN + BN * CN * 16) {
    transpose_body((float*)smem, xbf, xT, blk - BN * HN);
  } else {
    int i = (blk - BN * HN - BN * CN * 16) * 256 + threadIdx.x;
    Wvb[i] = __float2bfloat16(Wv[i]);
  }
}

// ---- standalone column attention
__global__ __launch_bounds__(256) void attn_col_k(
    const bf16* __restrict__ qF, const bf16* __restrict__ kF,
    const bf16* __restrict__ xT, bf16* __restrict__ thP) {
  __shared__ __align__(16) unsigned short psm[128 * 128];
  __shared__ float rsum[128];
  attn_body<true>(psm, rsum, qF, kF, xT, thP, blockIdx.x);
}

// ---- merge: twP[b][cg][h][w][8] += thP[b][cg][w][h][8]  (LDS-tiled transpose both sides)
__global__ __launch_bounds__(256) void packed_merge2(const bf16* __restrict__ thP,
                                                     bf16* __restrict__ twP) {
  __shared__ uint4 ts[32][33];
  const int tid = threadIdx.x;
  const int blk = blockIdx.x;
  const int tI = blk & 15;
  const int cg = (blk >> 4) & 31;
  const int b = blk >> 9;
  const int h0 = (tI >> 2) * 32, w0 = (tI & 3) * 32;
  const uint4* tp = (const uint4*)thP;
  uint4* tw = (uint4*)twP;
#pragma unroll
  for (int rep = 0; rep < 4; ++rep) {
    int cell = rep * 256 + tid;
    int ww = cell >> 5, hh = cell & 31;
    ts[ww][hh] = tp[(((size_t)b * 32 + cg) * 128 + (w0 + ww)) * 128 + (h0 + hh)];
  }
  __syncthreads();
#pragma unroll
  for (int rep = 0; rep < 4; ++rep) {
    int cell = rep * 256 + tid;
    int hh = cell >> 5, ww = cell & 31;
    size_t o = (((size_t)b * 32 + cg) * 128 + (h0 + hh)) * 128 + (w0 + ww);
    tw[o] = add8bf16(tw[o], ts[ww][hh]);
  }
}

// ---- final MFMA GEMM (r9-exact): out = gamma*(Wv @ t + 2bv) + residual; t = twP.
// XB: residual from bf16 xbf; else fp32 x.
template <bool XB>
__global__ __launch_bounds__(512) void final_mfma(
    const bf16* __restrict__ twP, const bf16* __restrict__ Wvb,
    const float* __restrict__ x, const bf16* __restrict__ xbf,
    const float* __restrict__ bv, const float* __restrict__ gamma,
    float* __restrict__ out) {
  __shared__ short As[256][64];
  __shared__ short Bs[128][64];
  const int tid = threadIdx.x;
  const int gid = blockIdx.x;
  const int b = gid >> 7, h = gid & 127;
  const int lane = tid & 63;
  const int wid = tid >> 6;
  const int wm = wid >> 1, wn = wid & 1;
  const int l15 = lane & 15, lg = lane >> 4;
  const unsigned short* twu = (const unsigned short*)twP;

  f32x4 acc[4][4];
#pragma unroll
  for (int m = 0; m < 4; ++m)
#pragma unroll
    for (int n = 0; n < 4; ++n)
#pragma unroll
      for (int e = 0; e < 4; ++e) acc[m][n][e] = 0.f;

#pragma unroll
  for (int k0i = 0; k0i < 4; ++k0i) {
    const int k0 = k0i * 64;
    __syncthreads();
#pragma unroll
    for (int p = 0; p < 4; ++p) {
      int idx = p * 512 + tid;
      int co = idx >> 3, cg = idx & 7;
      uint4 v = *(const uint4*)&Wvb[(size_t)co * 256 + k0 + cg * 8];
      *(uint4*)&As[co][(cg ^ (co & 7)) * 8] = v;
    }
#pragma unroll
    for (int p = 0; p < 2; ++p) {
      int idx = p * 512 + tid;
      int w = idx & 127, cgL = idx >> 7;
      int cg = (k0 >> 3) + cgL;
      size_t g16 = (((size_t)b * 32 + cg) * 128 + h) * 128 + w;
      uint4 v = *(const uint4*)&twu[g16 * 8];
      *(uint4*)&Bs[w][(cgL ^ (w & 7)) * 8] = v;
    }
    __syncthreads();
    short8 a[4][2], bb[4][2];
#pragma unroll
    for (int m = 0; m < 4; ++m)
#pragma unroll
      for (int kk = 0; kk < 2; ++kk) {
        int co = wm * 64 + m * 16 + l15;
        int cg = kk * 4 + lg;
        a[m][kk] = *(const short8*)&As[co][(cg ^ (co & 7)) * 8];
      }
#pragma unroll
    for (int n = 0; n < 4; ++n)
#pragma unroll
      for (int kk = 0; kk < 2; ++kk) {
        int w = wn * 64 + n * 16 + l15;
        int cg = kk * 4 + lg;
        bb[n][kk] = *(const short8*)&Bs[w][(cg ^ (w & 7)) * 8];
      }
#pragma unroll
    for (int kk = 0; kk < 2; ++kk)
#pragma unroll
      for (int m = 0; m < 4; ++m)
#pragma unroll
        for (int n = 0; n < 4; ++n)
          acc[m][n] = __builtin_amdgcn_mfma_f32_16x16x32_bf16(a[m][kk], bb[n][kk], acc[m][n], 0, 0, 0);
  }

  const float g = gamma[0];
  const unsigned short* xbu = (const unsigned short*)xbf;
  float bvv[4][4];
#pragma unroll
  for (int m = 0; m < 4; ++m)
#pragma unroll
    for (int rr = 0; rr < 4; ++rr)
      bvv[m][rr] = 2.0f * bv[wm * 64 + m * 16 + lg * 4 + rr];
#pragma unroll
  for (int m = 0; m < 4; ++m)
#pragma unroll
    for (int n = 0; n < 4; ++n) {
      int w = wn * 64 + n * 16 + l15;
#pragma unroll
      for (int rr = 0; rr < 4; ++rr) {
        int co = wm * 64 + m * 16 + lg * 4 + rr;
        size_t o = (((size_t)b * 256 + co) * 128 + h) * 128 + w;
        float res = XB ? bu2f(xbu[o]) : x[o];
        out[o] = g * (acc[m][n][rr] + bvv[m][rr]) + res;
      }
    }
}

extern "C" void kernel_launch(void* const* d_in, const int* in_sizes, int n_in,
                              void* d_out, int out_size, void* d_ws, size_t ws_size,
                              hipStream_t stream) {
  const float* x     = (const float*)d_in[0];
  const float* Wq    = (const float*)d_in[1];
  const float* bq    = (const float*)d_in[2];
  const float* Wk    = (const float*)d_in[3];
  const float* bk    = (const float*)d_in[4];
  const float* Wv    = (const float*)d_in[5];
  const float* bv    = (const float*)d_in[6];
  const float* gamma = (const float*)d_in[7];
  float* out = (float*)d_out;

  const size_t QSZ = (size_t)BN * HN * WN * CQn;  // 4,194,304
  const size_t XSZ = (size_t)BN * CN * HN * WN;   // 33,554,432
  bf16* wsb = (bf16*)d_ws;

  const size_t need_main = (2 * QSZ + 4 * XSZ + 65536) * sizeof(bf16);  // ~285 MB (proven)
  const size_t need_base = (2 * QSZ + 3 * XSZ + 65536) * sizeof(bf16);  // ~218 MB (proven)

  const int FUSED_GRID = BN * HN + BN * CN * 16 + 256;  // 1024 + 4096 + 256 = 5376

  if (ws_size >= need_main) {
    bf16* qF  = wsb;                      // [b][h][w][32]
    bf16* kF  = wsb + QSZ;                // [b][h][w][32]
    bf16* xbf = wsb + 2 * QSZ;            // [b][c][h][w] bf16 x (live to the end)
    bf16* xT  = wsb + 2 * QSZ + XSZ;      // [b][c][w][h]
    bf16* twP = wsb + 2 * QSZ + 2 * XSZ;  // c8-packed t accumulator
    bf16* thP = wsb + 2 * QSZ + 3 * XSZ;  // c8-packed t_h (transposed layout)
    bf16* Wvb = wsb + 2 * QSZ + 4 * XSZ;  // Wv bf16

    proj_qk3<<<2 * BN * HN, 256, 0, stream>>>(x, Wq, bq, Wk, bk, qF, kF, xbf);
    fused_mid<<<FUSED_GRID, 256, 0, stream>>>(qF, kF, xbf, twP, xT, Wv, Wvb);
    attn_col_k<<<BN * WN, 256, 0, stream>>>(qF, kF, xT, thP);
    packed_merge2<<<BN * 32 * 16, 256, 0, stream>>>(thP, twP);
    final_mfma<true><<<BN * HN, 512, 0, stream>>>(twP, Wvb, x, xbf, bv, gamma, out);
  } else if (ws_size >= need_base) {
    bf16* qF  = wsb;
    bf16* kF  = wsb + QSZ;
    bf16* xbf = wsb + 2 * QSZ;
    bf16* xT  = wsb + 2 * QSZ + XSZ;
    bf16* twP = wsb + 2 * QSZ + 2 * XSZ;
    bf16* Wvb = wsb + 2 * QSZ + 3 * XSZ;
    bf16* thP = xbf;  // alias: xbf dead after fused_mid (attn row + transpose both done)

    proj_qk3<<<2 * BN * HN, 256, 0, stream>>>(x, Wq, bq, Wk, bk, qF, kF, xbf);
    fused_mid<<<FUSED_GRID, 256, 0, stream>>>(qF, kF, xbf, twP, xT, Wv, Wvb);
    attn_col_k<<<BN * WN, 256, 0, stream>>>(qF, kF, xT, thP);
    packed_merge2<<<BN * 32 * 16, 256, 0, stream>>>(thP, twP);
    final_mfma<false><<<BN * HN, 512, 0, stream>>>(twP, Wvb, x, nullptr, bv, gamma, out);
  } else {
    hipMemsetAsync(d_out, 0x7f, (size_t)out_size * sizeof(float), stream);
  }
}

// Round 12
// 248.318 us; speedup vs baseline: 1.2117x; 1.2117x over previous
//
#include <hip/hip_runtime.h>
#include <hip/hip_bf16.h>

#define BN 8
#define CN 256
#define CQn 32
#define HN 128
#define WN 128

using bf16 = __hip_bfloat16;
typedef short short8 __attribute__((ext_vector_type(8)));
typedef float f32x4 __attribute__((ext_vector_type(4)));

__device__ __forceinline__ float ldf(const float* p) { return *p; }
__device__ __forceinline__ float ldf(const bf16* p) { return __bfloat162float(*p); }
__device__ __forceinline__ unsigned short f2bu(float v) {
  bf16 h = __float2bfloat16(v);
  return *(unsigned short*)&h;
}
__device__ __forceinline__ float bu2f(unsigned short u) {
  return __bfloat162float(*(const bf16*)&u);
}
__device__ __forceinline__ unsigned pack2(float a, float b) {
  return (unsigned)f2bu(a) | ((unsigned)f2bu(b) << 16);
}
__device__ __forceinline__ uint4 add8bf16(uint4 a, uint4 b) {
  union { uint4 v; unsigned short u[8]; } A, B, C;
  A.v = a; B.v = b;
#pragma unroll
  for (int e = 0; e < 8; ++e) C.u[e] = f2bu(bu2f(A.u[e]) + bu2f(B.u[e]));
  return C.v;
}

// ---- MFMA projection: qF/kF[b][h][w][32c] bf16, plus xbf[b][c][h][w] bf16 copy of x.
__global__ __launch_bounds__(256) void proj_qk3(
    const float* __restrict__ x, const float* __restrict__ Wq, const float* __restrict__ bq,
    const float* __restrict__ Wk, const float* __restrict__ bk,
    bf16* __restrict__ qF, bf16* __restrict__ kF, bf16* __restrict__ xbf) {
  __shared__ unsigned short xs[256 * 64];   // [c][w-local]; row=128B -> col reads 2-way (free)
  __shared__ unsigned short Ws[64 * 256];   // [oc][c], 16B-chunk swizzle slot = cg ^ (oc&7)
  const int tid = threadIdx.x;
  const int half = blockIdx.x & 1;
  const int bh = blockIdx.x >> 1;
  const int b = bh >> 7, h = bh & 127;
  const int w0 = half * 64;

#pragma unroll
  for (int it = 0; it < 8; ++it) {
    int idx = it * 256 + tid;           // 0..2047
    int oc = idx >> 5, cg = idx & 31;
    const float* wp = (oc < 32) ? &Wq[(size_t)oc * 256 + cg * 8]
                                : &Wk[(size_t)(oc - 32) * 256 + cg * 8];
    float4 f0 = *(const float4*)wp;
    float4 f1 = *(const float4*)(wp + 4);
    union { unsigned short u[8]; uint4 v; } t;
    t.u[0] = f2bu(f0.x); t.u[1] = f2bu(f0.y); t.u[2] = f2bu(f0.z); t.u[3] = f2bu(f0.w);
    t.u[4] = f2bu(f1.x); t.u[5] = f2bu(f1.y); t.u[6] = f2bu(f1.z); t.u[7] = f2bu(f1.w);
    *(uint4*)&Ws[oc * 256 + (cg ^ (oc & 7)) * 8] = t.v;
  }
  unsigned short* xbu = (unsigned short*)xbf;
#pragma unroll
  for (int it = 0; it < 16; ++it) {
    int idx = it * 256 + tid;           // 0..4095
    int c = idx >> 4, wc = idx & 15;
    size_t gix = (((size_t)b * 256 + c) * 128 + h) * 128 + w0 + wc * 4;
    float4 f = *(const float4*)&x[gix];
    union { unsigned short u[4]; uint2 v; } t;
    t.u[0] = f2bu(f.x); t.u[1] = f2bu(f.y); t.u[2] = f2bu(f.z); t.u[3] = f2bu(f.w);
    *(uint2*)&xs[c * 64 + wc * 4] = t.v;
    *(uint2*)&xbu[gix] = t.v;
  }
  __syncthreads();

  const int lane = tid & 63, wid = tid >> 6;  // 4 waves, each owns 16 w
  const int l15 = lane & 15, lg = lane >> 4;
  f32x4 acc[4];
#pragma unroll
  for (int mt = 0; mt < 4; ++mt)
#pragma unroll
    for (int e = 0; e < 4; ++e) acc[mt][e] = 0.f;

#pragma unroll
  for (int ks = 0; ks < 8; ++ks) {
    union { unsigned short u[8]; short8 s; } bf;
#pragma unroll
    for (int e = 0; e < 8; ++e)
      bf.u[e] = xs[(ks * 32 + lg * 8 + e) * 64 + wid * 16 + l15];
#pragma unroll
    for (int mt = 0; mt < 4; ++mt) {
      int oc = mt * 16 + l15;
      short8 af = *(const short8*)&Ws[oc * 256 + ((ks * 4 + lg) ^ (oc & 7)) * 8];
      acc[mt] = __builtin_amdgcn_mfma_f32_16x16x32_bf16(af, bf.s, acc[mt], 0, 0, 0);
    }
  }

  const int w = w0 + wid * 16 + l15;
#pragma unroll
  for (int mt = 0; mt < 4; ++mt) {
    float bb[4];
#pragma unroll
    for (int rr = 0; rr < 4; ++rr) {
      int ch = (mt & 1) * 16 + lg * 4 + rr;
      bb[rr] = (mt < 2) ? bq[ch] : bk[ch];
    }
    uint2 v;
    v.x = pack2(acc[mt][0] + bb[0], acc[mt][1] + bb[1]);
    v.y = pack2(acc[mt][2] + bb[2], acc[mt][3] + bb[3]);
    size_t base = (((size_t)b * 128 + h) * 128 + w) * 32 + (mt & 1) * 16 + lg * 4;
    if (mt < 2) *(uint2*)&((unsigned short*)qF)[base] = v;
    else        *(uint2*)&((unsigned short*)kF)[base] = v;
  }
}

// ---- transpose [p][r][c] -> [p][c][r], bf16 -> bf16
template <typename TIn>
__global__ __launch_bounds__(256) void transpose_bf16(const TIn* __restrict__ in,
                                                      bf16* __restrict__ out) {
  __shared__ float tile[32][33];
  const int blk = blockIdx.x;
  const int p = blk >> 4, t = blk & 15;
  const int r0 = (t >> 2) * 32, c0 = (t & 3) * 32;
  const int tx = threadIdx.x & 31, ty = threadIdx.x >> 5;
  const TIn* ip = in + (size_t)p * 128 * 128;
#pragma unroll
  for (int rr = 0; rr < 4; ++rr)
    tile[ty + 8 * rr][tx] = ldf(&ip[(r0 + ty + 8 * rr) * 128 + c0 + tx]);
  __syncthreads();
  bf16* op = out + (size_t)p * 128 * 128;
#pragma unroll
  for (int rr = 0; rr < 4; ++rr)
    op[(c0 + ty + 8 * rr) * 128 + r0 + tx] = __float2bfloat16(tile[tx][ty + 8 * rr]);
}

__global__ __launch_bounds__(256) void wv_to_bf16(const float* __restrict__ Wv,
                                                  bf16* __restrict__ Wvb) {
  int i = blockIdx.x * 256 + threadIdx.x;
  Wvb[i] = __float2bfloat16(Wv[i]);
}

// ---- MFMA criss-cross 1D attention (V source bf16).
template <bool COL>
__global__ __launch_bounds__(256) void attn_mfma(
    const bf16* __restrict__ qF, const bf16* __restrict__ kF,
    const bf16* __restrict__ vsrc, bf16* __restrict__ outP) {
  __shared__ unsigned short psm[128 * 128];  // P bf16, XOR-swizzled 16B slots
  __shared__ float rsum[128];
  const int tid = threadIdx.x;
  const int wid = tid >> 6;
  const int lane = tid & 63;
  const int l15 = lane & 15, lg = lane >> 4;
  const int b = blockIdx.x >> 7, r = blockIdx.x & 127;

  short8 qf[2];
  const int ti0 = wid * 2;
#pragma unroll
  for (int t2 = 0; t2 < 2; ++t2) {
    int i = (ti0 + t2) * 16 + l15;
    size_t base = COL ? (((size_t)b * 128 + i) * 128 + r) * 32
                      : (((size_t)b * 128 + r) * 128 + i) * 32;
    qf[t2] = *(const short8*)&qF[base + lg * 8];
  }
  f32x4 lgt[2][8];
#pragma unroll
  for (int t2 = 0; t2 < 2; ++t2)
#pragma unroll
    for (int tj = 0; tj < 8; ++tj)
#pragma unroll
      for (int e = 0; e < 4; ++e) lgt[t2][tj][e] = 0.f;
#pragma unroll
  for (int tj = 0; tj < 8; ++tj) {
    int j = tj * 16 + l15;
    size_t base = COL ? (((size_t)b * 128 + j) * 128 + r) * 32
                      : (((size_t)b * 128 + r) * 128 + j) * 32;
    short8 kf = *(const short8*)&kF[base + lg * 8];
#pragma unroll
    for (int t2 = 0; t2 < 2; ++t2)
      lgt[t2][tj] = __builtin_amdgcn_mfma_f32_16x16x32_bf16(kf, qf[t2], lgt[t2][tj], 0, 0, 0);
  }

#pragma unroll
  for (int t2 = 0; t2 < 2; ++t2) {
    const int i = (ti0 + t2) * 16 + l15;
    if (COL) {
#pragma unroll
      for (int tj = 0; tj < 8; ++tj)
#pragma unroll
        for (int rr = 0; rr < 4; ++rr)
          if (tj * 16 + lg * 4 + rr == i) lgt[t2][tj][rr] += 1.0f;
    }
    float m = -1e30f;
#pragma unroll
    for (int tj = 0; tj < 8; ++tj)
#pragma unroll
      for (int rr = 0; rr < 4; ++rr) m = fmaxf(m, lgt[t2][tj][rr]);
    m = fmaxf(m, __shfl_xor(m, 16, 64));
    m = fmaxf(m, __shfl_xor(m, 32, 64));
    float s = 0.f;
#pragma unroll
    for (int tj = 0; tj < 8; ++tj)
#pragma unroll
      for (int rr = 0; rr < 4; ++rr) {
        float e = __expf(lgt[t2][tj][rr] - m);
        lgt[t2][tj][rr] = e;
        s += e;
      }
    s += __shfl_xor(s, 16, 64);
    s += __shfl_xor(s, 32, 64);
    if (lg == 0) rsum[i] = s;
#pragma unroll
    for (int tj = 0; tj < 8; ++tj) {
      int slot = ((tj * 2) + (lg >> 1)) ^ (i & 7);
      int elem = i * 128 + slot * 8 + (lg & 1) * 4;
      uint2 v;
      v.x = pack2(lgt[t2][tj][0], lgt[t2][tj][1]);
      v.y = pack2(lgt[t2][tj][2], lgt[t2][tj][3]);
      *(uint2*)&psm[elem] = v;
    }
  }
  __syncthreads();

  float rinv[8];
#pragma unroll
  for (int nt = 0; nt < 8; ++nt) rinv[nt] = 1.0f / rsum[nt * 16 + l15];

  const int cbase = wid * 64;
  unsigned short* ou = (unsigned short*)outP;
#pragma unroll
  for (int cp = 0; cp < 2; ++cp) {
    short8 vf[2][4];
#pragma unroll
    for (int u = 0; u < 2; ++u) {
      int c = cbase + (cp * 2 + u) * 16 + l15;
#pragma unroll
      for (int ks = 0; ks < 4; ++ks)
        vf[u][ks] = *(const short8*)&vsrc[(((size_t)b * 256 + c) * 128 + r) * 128 + ks * 32 + lg * 8];
    }
    f32x4 acc[2][8];
#pragma unroll
    for (int u = 0; u < 2; ++u)
#pragma unroll
      for (int nt = 0; nt < 8; ++nt)
#pragma unroll
        for (int e = 0; e < 4; ++e) acc[u][nt][e] = 0.f;
#pragma unroll
    for (int ks = 0; ks < 4; ++ks)
#pragma unroll
      for (int nt = 0; nt < 8; ++nt) {
        int i = nt * 16 + l15;
        short8 pf = *(const short8*)&psm[i * 128 + (((ks * 4) + lg) ^ (i & 7)) * 8];
#pragma unroll
        for (int u = 0; u < 2; ++u)
          acc[u][nt] = __builtin_amdgcn_mfma_f32_16x16x32_bf16(vf[u][ks], pf, acc[u][nt], 0, 0, 0);
      }
#pragma unroll
    for (int u = 0; u < 2; ++u) {
      int ct = cp * 2 + u;
      int cg = wid * 8 + ct * 2 + (lg >> 1);
#pragma unroll
      for (int nt = 0; nt < 8; ++nt) {
        int i = nt * 16 + l15;
        float sc = rinv[nt];
        uint2 v;
        v.x = pack2(acc[u][nt][0] * sc, acc[u][nt][1] * sc);
        v.y = pack2(acc[u][nt][2] * sc, acc[u][nt][3] * sc);
        size_t elem = ((((size_t)b * 32 + cg) * 128 + r) * 128 + i) * 8 + (lg & 1) * 4;
        *(uint2*)&ou[elem] = v;
      }
    }
  }
}

// ---- merge: twP[b][cg][h][w][8] += thP[b][cg][w][h][8]  (LDS-tiled transpose both sides)
__global__ __launch_bounds__(256) void packed_merge2(const bf16* __restrict__ thP,
                                                     bf16* __restrict__ twP) {
  __shared__ uint4 ts[32][33];
  const int tid = threadIdx.x;
  const int blk = blockIdx.x;
  const int tI = blk & 15;
  const int cg = (blk >> 4) & 31;
  const int b = blk >> 9;
  const int h0 = (tI >> 2) * 32, w0 = (tI & 3) * 32;
  const uint4* tp = (const uint4*)thP;
  uint4* tw = (uint4*)twP;
#pragma unroll
  for (int rep = 0; rep < 4; ++rep) {
    int cell = rep * 256 + tid;
    int ww = cell >> 5, hh = cell & 31;
    ts[ww][hh] = tp[(((size_t)b * 32 + cg) * 128 + (w0 + ww)) * 128 + (h0 + hh)];
  }
  __syncthreads();
#pragma unroll
  for (int rep = 0; rep < 4; ++rep) {
    int cell = rep * 256 + tid;
    int hh = cell >> 5, ww = cell & 31;
    size_t o = (((size_t)b * 32 + cg) * 128 + (h0 + hh)) * 128 + (w0 + ww);
    tw[o] = add8bf16(tw[o], ts[ww][hh]);
  }
}

// ---- final MFMA GEMM: out = gamma*(Wv @ t + 2bv) + residual; t = twP (pre-merged).
// XB: residual from bf16 xbf (saves 67 MB); else fp32 x.
template <bool XB>
__global__ __launch_bounds__(512) void final_mfma(
    const bf16* __restrict__ twP, const bf16* __restrict__ Wvb,
    const float* __restrict__ x, const bf16* __restrict__ xbf,
    const float* __restrict__ bv, const float* __restrict__ gamma,
    float* __restrict__ out) {
  __shared__ short As[256][64];
  __shared__ short Bs[128][64];
  const int tid = threadIdx.x;
  const int gid = blockIdx.x;
  const int b = gid >> 7, h = gid & 127;
  const int lane = tid & 63;
  const int wid = tid >> 6;
  const int wm = wid >> 1, wn = wid & 1;
  const int l15 = lane & 15, lg = lane >> 4;
  const unsigned short* twu = (const unsigned short*)twP;

  f32x4 acc[4][4];
#pragma unroll
  for (int m = 0; m < 4; ++m)
#pragma unroll
    for (int n = 0; n < 4; ++n)
#pragma unroll
      for (int e = 0; e < 4; ++e) acc[m][n][e] = 0.f;

#pragma unroll
  for (int k0i = 0; k0i < 4; ++k0i) {
    const int k0 = k0i * 64;
    __syncthreads();
#pragma unroll
    for (int p = 0; p < 4; ++p) {
      int idx = p * 512 + tid;
      int co = idx >> 3, cg = idx & 7;
      uint4 v = *(const uint4*)&Wvb[(size_t)co * 256 + k0 + cg * 8];
      *(uint4*)&As[co][(cg ^ (co & 7)) * 8] = v;
    }
#pragma unroll
    for (int p = 0; p < 2; ++p) {
      int idx = p * 512 + tid;
      int w = idx & 127, cgL = idx >> 7;
      int cg = (k0 >> 3) + cgL;
      size_t g16 = (((size_t)b * 32 + cg) * 128 + h) * 128 + w;
      uint4 v = *(const uint4*)&twu[g16 * 8];
      *(uint4*)&Bs[w][(cgL ^ (w & 7)) * 8] = v;
    }
    __syncthreads();
    short8 a[4][2], bb[4][2];
#pragma unroll
    for (int m = 0; m < 4; ++m)
#pragma unroll
      for (int kk = 0; kk < 2; ++kk) {
        int co = wm * 64 + m * 16 + l15;
        int cg = kk * 4 + lg;
        a[m][kk] = *(const short8*)&As[co][(cg ^ (co & 7)) * 8];
      }
#pragma unroll
    for (int n = 0; n < 4; ++n)
#pragma unroll
      for (int kk = 0; kk < 2; ++kk) {
        int w = wn * 64 + n * 16 + l15;
        int cg = kk * 4 + lg;
        bb[n][kk] = *(const short8*)&Bs[w][(cg ^ (w & 7)) * 8];
      }
#pragma unroll
    for (int kk = 0; kk < 2; ++kk)
#pragma unroll
      for (int m = 0; m < 4; ++m)
#pragma unroll
        for (int n = 0; n < 4; ++n)
          acc[m][n] = __builtin_amdgcn_mfma_f32_16x16x32_bf16(a[m][kk], bb[n][kk], acc[m][n], 0, 0, 0);
  }

  const float g = gamma[0];
  const unsigned short* xbu = (const unsigned short*)xbf;
  float bvv[4][4];
#pragma unroll
  for (int m = 0; m < 4; ++m)
#pragma unroll
    for (int rr = 0; rr < 4; ++rr)
      bvv[m][rr] = 2.0f * bv[wm * 64 + m * 16 + lg * 4 + rr];
#pragma unroll
  for (int m = 0; m < 4; ++m)
#pragma unroll
    for (int n = 0; n < 4; ++n) {
      int w = wn * 64 + n * 16 + l15;
#pragma unroll
      for (int rr = 0; rr < 4; ++rr) {
        int co = wm * 64 + m * 16 + lg * 4 + rr;
        size_t o = (((size_t)b * 256 + co) * 128 + h) * 128 + w;
        float res = XB ? bu2f(xbu[o]) : x[o];
        out[o] = g * (acc[m][n][rr] + bvv[m][rr]) + res;
      }
    }
}

extern "C" void kernel_launch(void* const* d_in, const int* in_sizes, int n_in,
                              void* d_out, int out_size, void* d_ws, size_t ws_size,
                              hipStream_t stream) {
  const float* x     = (const float*)d_in[0];
  const float* Wq    = (const float*)d_in[1];
  const float* bq    = (const float*)d_in[2];
  const float* Wk    = (const float*)d_in[3];
  const float* bk    = (const float*)d_in[4];
  const float* Wv    = (const float*)d_in[5];
  const float* bv    = (const float*)d_in[6];
  const float* gamma = (const float*)d_in[7];
  float* out = (float*)d_out;

  const size_t QSZ = (size_t)BN * HN * WN * CQn;  // 4,194,304
  const size_t XSZ = (size_t)BN * CN * HN * WN;   // 33,554,432
  bf16* wsb = (bf16*)d_ws;

  const size_t need_main = (2 * QSZ + 4 * XSZ + 65536) * sizeof(bf16);  // ~285 MB (proven)
  const size_t need_base = (2 * QSZ + 3 * XSZ + 65536) * sizeof(bf16);  // ~218 MB (proven)

  if (ws_size >= need_main) {
    bf16* qF  = wsb;                      // [b][h][w][32]
    bf16* kF  = wsb + QSZ;                // [b][h][w][32]
    bf16* xbf = wsb + 2 * QSZ;            // [b][c][h][w] bf16 copy of x (live to the end)
    bf16* xT  = wsb + 2 * QSZ + XSZ;      // [b][c][w][h]
    bf16* twP = wsb + 2 * QSZ + 2 * XSZ;  // c8-packed t accumulator
    bf16* thP = wsb + 2 * QSZ + 3 * XSZ;  // c8-packed t_h (transposed layout)
    bf16* Wvb = wsb + 2 * QSZ + 4 * XSZ;  // Wv bf16

    proj_qk3<<<2 * BN * HN, 256, 0, stream>>>(x, Wq, bq, Wk, bk, qF, kF, xbf);
    wv_to_bf16<<<256, 256, 0, stream>>>(Wv, Wvb);
    transpose_bf16<bf16><<<BN * CN * 16, 256, 0, stream>>>(xbf, xT);
    attn_mfma<false><<<BN * HN, 256, 0, stream>>>(qF, kF, xbf, twP);
    attn_mfma<true><<<BN * WN, 256, 0, stream>>>(qF, kF, xT, thP);
    packed_merge2<<<BN * 32 * 16, 256, 0, stream>>>(thP, twP);
    final_mfma<true><<<BN * HN, 512, 0, stream>>>(twP, Wvb, x, xbf, bv, gamma, out);
  } else if (ws_size >= need_base) {
    // r5-proven structure (thP aliases xbf; residual from fp32 x)
    bf16* qF  = wsb;
    bf16* kF  = wsb + QSZ;
    bf16* xbf = wsb + 2 * QSZ;
    bf16* xT  = wsb + 2 * QSZ + XSZ;
    bf16* twP = wsb + 2 * QSZ + 2 * XSZ;
    bf16* Wvb = wsb + 2 * QSZ + 3 * XSZ;
    bf16* thP = xbf;  // alias: xbf dead after attn row in this path

    proj_qk3<<<2 * BN * HN, 256, 0, stream>>>(x, Wq, bq, Wk, bk, qF, kF, xbf);
    wv_to_bf16<<<256, 256, 0, stream>>>(Wv, Wvb);
    transpose_bf16<bf16><<<BN * CN * 16, 256, 0, stream>>>(xbf, xT);
    attn_mfma<false><<<BN * HN, 256, 0, stream>>>(qF, kF, xbf, twP);
    attn_mfma<true><<<BN * WN, 256, 0, stream>>>(qF, kF, xT, thP);
    packed_merge2<<<BN * 32 * 16, 256, 0, stream>>>(thP, twP);
    final_mfma<false><<<BN * HN, 512, 0, stream>>>(twP, Wvb, x, nullptr, bv, gamma, out);
  } else {
    hipMemsetAsync(d_out, 0x7f, (size_t)out_size * sizeof(float), stream);
  }
}